// Round 13
// baseline (54.355 us; speedup 1.0000x reference)
//
#include <hip/hip_runtime.h>
#include <hip/hip_bf16.h>

// Problem constants (B, T, C, HS) from the reference.
#define NB 256
#define NT 256
#define NC 384
#define NH 64
#define NW 192              // 3 * NH concatenated output cols
#define WT_ELEMS (NW * NC)  // Wt2 bf16 elements = 73728 (147456 B)

typedef short bf16x8 __attribute__((ext_vector_type(8)));
typedef float f32x4 __attribute__((ext_vector_type(4)));

__device__ __forceinline__ unsigned short f2bf(float f) {
  union { float f; unsigned int i; } c;
  c.f = f;
  const unsigned int r = c.i + 0x7fffu + ((c.i >> 16) & 1u);
  return (unsigned short)(r >> 16);
}

__device__ __forceinline__ unsigned short f2bf_hw(float f) {
  __hip_bfloat16 b = __float2bfloat16(f);
  return *reinterpret_cast<unsigned short*>(&b);
}

// ---------------------------------------------------------------------------
// Kernel 0: build FRAGMENT-MAJOR weights (unchanged since round 11).
// Wt2[((kt*12 + ni)*64 + lane)*8 + j] = W_sel[k][h]:
//   n = ni*16 + (lane&15), k = kt*32 + (lane>>4)*8 + j.
// ---------------------------------------------------------------------------
__global__ __launch_bounds__(256) void w_prep_kernel(
    const float* __restrict__ Wq,
    const float* __restrict__ Wk,
    const float* __restrict__ Wv,
    unsigned short* __restrict__ Wt2) {
  const int o = blockIdx.x * 256 + threadIdx.x;
  if (o >= WT_ELEMS) return;
  const int j = o & 7;
  const int lane = (o >> 3) & 63;
  const int fi = o >> 9;  // kt*12 + ni
  const int ni = fi % 12;
  const int kt = fi / 12;
  const int n = ni * 16 + (lane & 15);
  const int k = kt * 32 + ((lane >> 4) << 3) + j;
  const float* W = (n < 64) ? Wq : (n < 128) ? Wk : Wv;
  Wt2[o] = f2bf(W[k * NH + (n & 63)]);
}

// ---------------------------------------------------------------------------
// Kernel 1 (round 13): fused proj+attn, K-THIRDS with long contiguous x runs.
//
// Rounds 7-12 post-mortem: FOUR structurally different proj designs all tie
// at ~43-45 us with x streaming at only ~3.3 TB/s. Common mechanism never
// addressed: BK=32 k-slicing reads 128 B of every 1536 B row per pass (12
// passes) -> each 2 KB DRAM page activated ~12x for ~170 B/visit (~8% row
// utilization). Fix: split K into THIRDS (128 cols = 512 B/row contiguous,
// 3 passes, ~33% row utilization, mergeable requests).
//
// Per wave (barrier-free x path): private LDS x-buffer [2 groups][16 rows]
// [128 cols] bf16 (8 KB/wave, cvt once, XOR-swizzled 16B chunks:
// ch' = ch ^ (row&7)); refilled per third from 16 float4/lane sequential
// bursts that stay in flight under the previous third's compute.
// W fragment-major, DOUBLE-BUFFERED in LDS (2 x 48 KB via global_load_lds).
// LDS = 64 KB xbufs + 96 KB W = 163840 B exactly (1 block/CU).
//
// vmcnt ledger (per-thread, wave-uniform):
//   XLOAD(0)=16 | WSTAGE(0,0)+WSTAGE(1,1)=+12 -> 28
//   vmcnt(12): x(0) done -> XWRITE; XLOAD(1) -> 28
//   vmcnt(16): W(0),W(1) done; lgkm0; barrier; COMPUTE third0 (Wbuf0)
//   barrier; WSTAGE(0,2) -> 22
//   vmcnt(6): x(1) done -> XWRITE; XLOAD(2) -> 22; lgkm0
//   COMPUTE third1 (Wbuf1)   [22 ops in flight under compute]
//   vmcnt(0): x(2)+W(2) done -> XWRITE; lgkm0; barrier; COMPUTE third2 (Wbuf0)
// Attn phase unchanged (verified rounds 2-12); scatter after __syncthreads.
// mfma_f32_16x16x32_bf16 layouts (HW-verified round 2):
//   A/B: k = (l>>4)*8+j contiguous;  D: n = l&15, m = (l>>4)*4 + r.
// ---------------------------------------------------------------------------
__global__ __launch_bounds__(512, 2) void fused_qkv_attn_kernel(
    const float* __restrict__ x,
    const unsigned short* __restrict__ Wt2,
    float* __restrict__ out) {
  __shared__ __align__(16) unsigned char lds[163840];  // 160 KB exactly

  const int tid = threadIdx.x;
  const int w = tid >> 6;
  const int lane = tid & 63;
  const int l15 = lane & 15;
  const int lg = lane >> 4;
  const int b = blockIdx.x;
  const int row0 = b * NT;              // this block's 256 x-rows
  const int qt = (w < 4) ? w : 11 - w;  // causal-balanced q-tile per wave
  const int wbase = qt * 32;            // wave's 32 rows (block-local)

  f32x4 acc[2][12];
#pragma unroll
  for (int mi = 0; mi < 2; ++mi)
#pragma unroll
    for (int ni = 0; ni < 12; ++ni)
#pragma unroll
      for (int r = 0; r < 4; ++r) acc[mi][ni][r] = 0.f;

  float4 xr[16];  // all indices compile-time (full unroll) -> registers

  // Load third T: wave's 32 rows x 128 cols fp32, 512 B/row contiguous.
  // idx = i*64+lane: row = idx>>5 (2 rows per instr), c = idx&31.
#define XLOAD(T)                                                              \
  {                                                                           \
    _Pragma("unroll") for (int i = 0; i < 16; ++i) {                          \
      const int idx_ = i * 64 + lane;                                         \
      const int r_ = idx_ >> 5, c_ = idx_ & 31;                               \
      xr[i] = *reinterpret_cast<const float4*>(                               \
          x + (size_t)(row0 + wbase + r_) * NC + (T)*128 + c_ * 4);           \
    }                                                                         \
  }

  // cvt + write into wave-private swizzled buffer (no barrier needed).
#define XWRITE()                                                              \
  {                                                                           \
    _Pragma("unroll") for (int i = 0; i < 16; ++i) {                          \
      const int idx_ = i * 64 + lane;                                         \
      const int r_ = idx_ >> 5, c_ = idx_ & 31;                               \
      ushort4 t_;                                                             \
      t_.x = f2bf_hw(xr[i].x); t_.y = f2bf_hw(xr[i].y);                       \
      t_.z = f2bf_hw(xr[i].z); t_.w = f2bf_hw(xr[i].w);                       \
      *reinterpret_cast<ushort4*>(lds + w * 8192 + (r_ >> 4) * 4096 +         \
                                  (r_ & 15) * 256 +                           \
                                  ((((c_ >> 1) ^ (r_ & 7)) << 4)) +           \
                                  (c_ & 1) * 8) = t_;                         \
    }                                                                         \
  }

  // Stage 48 KB W-third (contiguous in Wt2) into LDS dbuf: 6 x 16B DMA/thr.
#define WSTAGE(BUF, T)                                                        \
  {                                                                           \
    _Pragma("unroll") for (int j = 0; j < 6; ++j) {                           \
      const int ch_ = j * 512 + tid;                                          \
      __builtin_amdgcn_global_load_lds(                                       \
          (const __attribute__((address_space(1))) void*)(Wt2 + (T)*24576 +   \
                                                          ch_ * 8),           \
          (__attribute__((address_space(3))) void*)(lds + 65536 +             \
                                                    (BUF)*49152 + ch_ * 16),  \
          16, 0, 0);                                                          \
    }                                                                         \
  }

  // Compute one third: 4 k-tiles x 12 n-tiles x 2 groups, all from LDS.
#define CTHIRD(BUF)                                                           \
  {                                                                           \
    _Pragma("unroll") for (int kl = 0; kl < 4; ++kl) {                        \
      const int ch_ = ((kl * 4 + lg) ^ (l15 & 7)) << 4;                       \
      const bf16x8 af0 = *reinterpret_cast<const bf16x8*>(                    \
          lds + w * 8192 + l15 * 256 + ch_);                                  \
      const bf16x8 af1 = *reinterpret_cast<const bf16x8*>(                    \
          lds + w * 8192 + 4096 + l15 * 256 + ch_);                           \
      _Pragma("unroll") for (int ni = 0; ni < 12; ++ni) {                     \
        const bf16x8 bfr = *reinterpret_cast<const bf16x8*>(                  \
            lds + 65536 + (BUF)*49152 + (kl * 12 + ni) * 1024 + lane * 16);   \
        acc[0][ni] = __builtin_amdgcn_mfma_f32_16x16x32_bf16(                 \
            af0, bfr, acc[0][ni], 0, 0, 0);                                   \
        acc[1][ni] = __builtin_amdgcn_mfma_f32_16x16x32_bf16(                 \
            af1, bfr, acc[1][ni], 0, 0, 0);                                   \
      }                                                                       \
    }                                                                         \
  }

  // ---- proj: 3 thirds ----
  XLOAD(0);                                            // 16 in flight
  WSTAGE(0, 0);
  WSTAGE(1, 1);                                        // 28
  asm volatile("s_waitcnt vmcnt(12)" ::: "memory");    // x(0) done
  XWRITE();
  XLOAD(1);                                            // 28
  asm volatile("s_waitcnt vmcnt(16)" ::: "memory");    // W(0),W(1) done
  asm volatile("s_waitcnt lgkmcnt(0)" ::: "memory");
  __builtin_amdgcn_s_barrier();
  CTHIRD(0);                                           // third 0
  __builtin_amdgcn_s_barrier();                        // all done with Wbuf0
  WSTAGE(0, 2);                                        // 22
  asm volatile("s_waitcnt vmcnt(6)" ::: "memory");     // x(1) done
  XWRITE();
  XLOAD(2);                                            // 22
  asm volatile("s_waitcnt lgkmcnt(0)" ::: "memory");
  CTHIRD(1);                                           // third 1 (loads fly)
  asm volatile("s_waitcnt vmcnt(0)" ::: "memory");     // x(2) + W(2) done
  XWRITE();
  asm volatile("s_waitcnt lgkmcnt(0)" ::: "memory");
  __builtin_amdgcn_s_barrier();                        // W(2) visible to all
  CTHIRD(0);                                           // third 2

  __syncthreads();  // all compute done before LDS is repurposed

  // ---- epilogue: scatter acc into attention LDS layouts (bf16) ----
  unsigned short* Kls = reinterpret_cast<unsigned short*>(lds);           // 32K
  unsigned short* Vtls = reinterpret_cast<unsigned short*>(lds + 32768);  // 32K
  unsigned short* Qls = reinterpret_cast<unsigned short*>(lds + 65536);   // 32K
  unsigned short* Pls = reinterpret_cast<unsigned short*>(lds + 98304);   // 20K

#pragma unroll
  for (int mi = 0; mi < 2; ++mi)
#pragma unroll
    for (int ni = 0; ni < 12; ++ni) {
      const int n = ni * 16 + l15;
#pragma unroll
      for (int r = 0; r < 4; ++r) {
        const int srow = wbase + mi * 16 + lg * 4 + r;
        const unsigned short val = f2bf_hw(acc[mi][ni][r]);
        if (ni < 4) {
          Qls[srow * 64 + (n ^ ((srow & 7) << 3))] = val;
        } else if (ni < 8) {
          const int h = n - 64;
          Kls[srow * 64 + (h ^ ((srow & 7) << 3))] = val;
        } else {
          const int h = n - 128;
          Vtls[h * 256 + (srow ^ ((h & 7) << 3))] = val;
        }
      }
    }
  __syncthreads();

  // ---- attention phase (flash, per-wave independent; unchanged) ----
  const int q0 = wbase;
  bf16x8 a_q[2][2];
#pragma unroll
  for (int mi = 0; mi < 2; ++mi)
#pragma unroll
    for (int ks = 0; ks < 2; ++ks) {
      const int srow = q0 + mi * 16 + l15;
      a_q[mi][ks] = *reinterpret_cast<const bf16x8*>(
          Qls + srow * 64 + ((ks * 32 + lg * 8) ^ ((srow & 7) << 3)));
    }

  f32x4 o[2][4];
  float mrun[2][4], lrun[2][4];
#pragma unroll
  for (int mi = 0; mi < 2; ++mi)
#pragma unroll
    for (int r = 0; r < 4; ++r) {
      mrun[mi][r] = -3.0e38f;
      lrun[mi][r] = 0.f;
#pragma unroll
      for (int hi = 0; hi < 4; ++hi) o[mi][hi][r] = 0.f;
    }

  unsigned short* Pw = Pls + w * 1280;  // per-wave [32][40]

  for (int j = 0; j <= qt; ++j) {
    f32x4 s_acc[2][2];
#pragma unroll
    for (int mi = 0; mi < 2; ++mi)
#pragma unroll
      for (int si = 0; si < 2; ++si)
#pragma unroll
        for (int r = 0; r < 4; ++r) s_acc[mi][si][r] = 0.f;

#pragma unroll
    for (int ks = 0; ks < 2; ++ks) {
      bf16x8 bk[2];
#pragma unroll
      for (int si = 0; si < 2; ++si) {
        const int srow = j * 32 + si * 16 + l15;
        const int kel = ks * 32 + lg * 8;
        bk[si] = *reinterpret_cast<const bf16x8*>(
            Kls + srow * 64 + (kel ^ ((srow & 7) << 3)));
      }
#pragma unroll
      for (int mi = 0; mi < 2; ++mi)
#pragma unroll
        for (int si = 0; si < 2; ++si)
          s_acc[mi][si] = __builtin_amdgcn_mfma_f32_16x16x32_bf16(
              a_q[mi][ks], bk[si], s_acc[mi][si], 0, 0, 0);
    }

    const bool diag = (j == qt);
#pragma unroll
    for (int mi = 0; mi < 2; ++mi) {
#pragma unroll
      for (int r = 0; r < 4; ++r) {
        const int mloc = mi * 16 + lg * 4 + r;
        float v0 = s_acc[mi][0][r] * 0.125f;
        float v1 = s_acc[mi][1][r] * 0.125f;
        if (diag) {
          if (l15 > mloc) v0 = -3.0e38f;
          if (16 + l15 > mloc) v1 = -3.0e38f;
        }
        float pm = fmaxf(v0, v1);
        pm = fmaxf(pm, __shfl_xor(pm, 1, 16));
        pm = fmaxf(pm, __shfl_xor(pm, 2, 16));
        pm = fmaxf(pm, __shfl_xor(pm, 4, 16));
        pm = fmaxf(pm, __shfl_xor(pm, 8, 16));
        const float mnew = fmaxf(mrun[mi][r], pm);
        const float alpha = __expf(mrun[mi][r] - mnew);
        mrun[mi][r] = mnew;
        const float p0 = __expf(v0 - mnew);
        const float p1 = __expf(v1 - mnew);
        float ps = p0 + p1;
        ps += __shfl_xor(ps, 1, 16);
        ps += __shfl_xor(ps, 2, 16);
        ps += __shfl_xor(ps, 4, 16);
        ps += __shfl_xor(ps, 8, 16);
        lrun[mi][r] = lrun[mi][r] * alpha + ps;
#pragma unroll
        for (int hi = 0; hi < 4; ++hi) o[mi][hi][r] *= alpha;
        Pw[mloc * 40 + l15] = f2bf(p0);
        Pw[mloc * 40 + 16 + l15] = f2bf(p1);
      }
    }

    bf16x8 pa[2];
#pragma unroll
    for (int mt = 0; mt < 2; ++mt)
      pa[mt] = *reinterpret_cast<const bf16x8*>(
          Pw + (mt * 16 + l15) * 40 + lg * 8);
#pragma unroll
    for (int hi = 0; hi < 4; ++hi) {
      const int h = hi * 16 + l15;
      const int sel = j * 32 + lg * 8;
      const bf16x8 bv = *reinterpret_cast<const bf16x8*>(
          Vtls + h * 256 + (sel ^ ((h & 7) << 3)));
#pragma unroll
      for (int mt = 0; mt < 2; ++mt)
        o[mt][hi] = __builtin_amdgcn_mfma_f32_16x16x32_bf16(
            pa[mt], bv, o[mt][hi], 0, 0, 0);
    }
  }

  // ---- out store ----
  float* og = out + ((size_t)b * NT + q0) * NH;
#pragma unroll
  for (int mi = 0; mi < 2; ++mi)
#pragma unroll
    for (int r = 0; r < 4; ++r) {
      const float inv = 1.f / lrun[mi][r];
      const int m = mi * 16 + lg * 4 + r;
#pragma unroll
      for (int hi = 0; hi < 4; ++hi)
        og[m * 64 + hi * 16 + l15] = o[mi][hi][r] * inv;
    }
}

// ---------------------------------------------------------------------------
extern "C" void kernel_launch(void* const* d_in, const int* in_sizes, int n_in,
                              void* d_out, int out_size, void* d_ws,
                              size_t ws_size, hipStream_t stream) {
  const float* x  = (const float*)d_in[0];
  const float* Wq = (const float*)d_in[1];
  const float* Wk = (const float*)d_in[2];
  const float* Wv = (const float*)d_in[3];
  unsigned short* Wt2 = (unsigned short*)d_ws;  // 147 KB, fragment-major
  float* out = (float*)d_out;

  w_prep_kernel<<<dim3((WT_ELEMS + 255) / 256), dim3(256), 0, stream>>>(
      Wq, Wk, Wv, Wt2);
  fused_qkv_attn_kernel<<<dim3(NB), dim3(512), 0, stream>>>(x, Wt2, out);
}

// Round 14
// 41.114 us; speedup vs baseline: 1.3220x; 1.3220x over previous
//
#include <hip/hip_runtime.h>
#include <hip/hip_bf16.h>

// Problem constants (B, T, C, HS) from the reference.
#define NB 256
#define NT 256
#define NC 384
#define NH 64
#define NW 192              // 3 * NH concatenated output cols
#define WT_ELEMS (NW * NC)  // Wt2 bf16 elements = 73728 (147456 B)

typedef short bf16x8 __attribute__((ext_vector_type(8)));
typedef float f32x4 __attribute__((ext_vector_type(4)));

__device__ __forceinline__ unsigned short f2bf(float f) {
  union { float f; unsigned int i; } c;
  c.f = f;
  const unsigned int r = c.i + 0x7fffu + ((c.i >> 16) & 1u);
  return (unsigned short)(r >> 16);
}

__device__ __forceinline__ unsigned short f2bf_hw(float f) {
  __hip_bfloat16 b = __float2bfloat16(f);
  return *reinterpret_cast<unsigned short*>(&b);
}

__device__ __forceinline__ bf16x8 cvt8(float4 lo, float4 hi) {
  union { bf16x8 v; unsigned short u[8]; } au;
  au.u[0] = f2bf_hw(lo.x); au.u[1] = f2bf_hw(lo.y);
  au.u[2] = f2bf_hw(lo.z); au.u[3] = f2bf_hw(lo.w);
  au.u[4] = f2bf_hw(hi.x); au.u[5] = f2bf_hw(hi.y);
  au.u[6] = f2bf_hw(hi.z); au.u[7] = f2bf_hw(hi.w);
  return au.v;
}

// ---------------------------------------------------------------------------
// Kernel 0: build FRAGMENT-MAJOR weights (unchanged since round 11).
// Wt2[((kt*12 + ni)*64 + lane)*8 + j] = W_sel[k][h]:
//   n = ni*16 + (lane&15), k = kt*32 + (lane>>4)*8 + j.
// ---------------------------------------------------------------------------
__global__ __launch_bounds__(256) void w_prep_kernel(
    const float* __restrict__ Wq,
    const float* __restrict__ Wk,
    const float* __restrict__ Wv,
    unsigned short* __restrict__ Wt2) {
  const int o = blockIdx.x * 256 + threadIdx.x;
  if (o >= WT_ELEMS) return;
  const int j = o & 7;
  const int lane = (o >> 3) & 63;
  const int fi = o >> 9;  // kt*12 + ni
  const int ni = fi % 12;
  const int kt = fi / 12;
  const int n = ni * 16 + (lane & 15);
  const int k = kt * 32 + ((lane >> 4) << 3) + j;
  const float* W = (n < 64) ? Wq : (n < 128) ? Wk : Wv;
  Wt2[o] = f2bf(W[k * NH + (n & 63)]);
}

// ---------------------------------------------------------------------------
// Kernel 1 (round 14): fused proj+attn, 16 WAVES/BLOCK (TLP attack).
//
// Rounds 7-13 post-mortem: five proj structures tie at ~43-45 us with the
// latency/occupancy counter signature (MfmaUtil 6, VALU 10, HBM 9%,
// Occupancy 20% = 2 waves/SIMD). The one untested lever: TLP. This round:
// block = 1024 thr = 16 waves (4/SIMD), per-wave tiles halved (16 proj
// rows, acc[12] = 48 VGPR -> fits the 128-VGPR cap of 4 waves/SIMD).
//
// Wave->q-tile map: pandiagonal magic square (nibble-packed constant):
// every consecutive-4 AND stride-4 group of waves sums to 30 -> causal
// work balanced per SIMD under either wave->SIMD convention.
//
// Proj: W fragment-major resident in LDS (147456 B, staged once via
// global_load_lds, 9 chunks/thread); x direct-to-reg 3-deep named sets
// (A/B/C, 2 float4 each); no barriers in the k-loop.
// Attn: 16-row q-tiles, 32-row K-blocks, parity diagonal mask
// (qt even: v0 masked, v1 dead; qt odd: v0 full, v1 masked).
// LDS reuse after proj: Kls 32K | Vtls 32K | Qls 32K | Pls 16x1280B.
// mfma_f32_16x16x32_bf16 layouts (HW-verified round 2):
//   A/B: k = (l>>4)*8+j contiguous;  D: n = l&15, m = (l>>4)*4 + r.
// ---------------------------------------------------------------------------
__global__ __launch_bounds__(1024, 4) void fused_qkv_attn_kernel(
    const float* __restrict__ x,
    const unsigned short* __restrict__ Wt2,
    float* __restrict__ out) {
  __shared__ __align__(16) unsigned char lds[147456];

  const int tid = threadIdx.x;
  const int w = tid >> 6;  // 0..15
  const int lane = tid & 63;
  const int l15 = lane & 15;
  const int lg = lane >> 4;
  const int b = blockIdx.x;
  const int row0 = b * NT;
  // qt = magic[w]: nibble-packed pandiagonal magic square of 0..15.
  const int qt =
      (int)((0x583E2F49C1A7B6D0ull >> (w << 2)) & 15ull);
  const int wbase = qt * 16;  // wave's 16 q-rows (block-local)

  f32x4 acc[12];
#pragma unroll
  for (int ni = 0; ni < 12; ++ni)
#pragma unroll
    for (int r = 0; r < 4; ++r) acc[ni][r] = 0.f;

  // ---- stage ALL of W into LDS (9 x 16B DMA per thread, linear) ----
#pragma unroll
  for (int i = 0; i < 9; ++i) {
    const int idx = i * 1024 + tid;  // 16B chunk index, 9216 total
    __builtin_amdgcn_global_load_lds(
        (const __attribute__((address_space(1))) void*)(Wt2 + idx * 8),
        (__attribute__((address_space(3))) void*)(lds + idx * 16), 16, 0, 0);
  }

  // ---- A-pipeline prologue: issue tiles 0,1,2 into named sets ----
  const float* xa0 = x + (size_t)(row0 + wbase + l15) * NC + lg * 8;

  float4 aA0, aA1, aB0, aB1, aC0, aC1;

#define LOADA(S, KT)                                                          \
  do {                                                                        \
    a##S##0 = *reinterpret_cast<const float4*>(xa0 + (KT)*32);                \
    a##S##1 = *reinterpret_cast<const float4*>(xa0 + (KT)*32 + 4);            \
  } while (0)

  LOADA(A, 0);
  LOADA(B, 1);
  LOADA(C, 2);

  // Drain everything once (prologue only): guarantees the W image is
  // resident for every wave before the barrier, regardless of issue order.
  asm volatile("s_waitcnt vmcnt(0)" ::: "memory");
  __builtin_amdgcn_s_barrier();

  // ---- proj loop: consume set, refill 3 ahead; W from LDS ----
  const unsigned short* Wl =
      reinterpret_cast<const unsigned short*>(lds) + lane * 8;

#define STEP(S, KT)                                                           \
  do {                                                                        \
    const bf16x8 afr = cvt8(a##S##0, a##S##1);                                \
    if ((KT) + 3 < 12) LOADA(S, (KT) + 3);                                    \
    _Pragma("unroll") for (int ni = 0; ni < 12; ++ni) {                       \
      const bf16x8 bfr = *reinterpret_cast<const bf16x8*>(                    \
          Wl + (size_t)((KT)*12 + ni) * 512);                                 \
      acc[ni] = __builtin_amdgcn_mfma_f32_16x16x32_bf16(                      \
          afr, bfr, acc[ni], 0, 0, 0);                                        \
    }                                                                         \
  } while (0)

  STEP(A, 0);  STEP(B, 1);  STEP(C, 2);
  STEP(A, 3);  STEP(B, 4);  STEP(C, 5);
  STEP(A, 6);  STEP(B, 7);  STEP(C, 8);
  STEP(A, 9);  STEP(B, 10); STEP(C, 11);

  // All waves done reading the W image before overwriting LDS with K/V/Q.
  __syncthreads();

  // ---- epilogue: scatter acc into attention LDS layouts (bf16) ----
  unsigned short* Kls = reinterpret_cast<unsigned short*>(lds);           // 32K
  unsigned short* Vtls = reinterpret_cast<unsigned short*>(lds + 32768);  // 32K
  unsigned short* Qls = reinterpret_cast<unsigned short*>(lds + 65536);   // 32K
  unsigned short* Pls = reinterpret_cast<unsigned short*>(lds + 98304);   // 20K

#pragma unroll
  for (int ni = 0; ni < 12; ++ni) {
    const int n = ni * 16 + l15;
#pragma unroll
    for (int r = 0; r < 4; ++r) {
      const int srow = wbase + lg * 4 + r;
      const unsigned short val = f2bf_hw(acc[ni][r]);
      if (ni < 4) {
        Qls[srow * 64 + (n ^ ((srow & 7) << 3))] = val;
      } else if (ni < 8) {
        const int h = n - 64;
        Kls[srow * 64 + (h ^ ((srow & 7) << 3))] = val;
      } else {
        const int h = n - 128;
        Vtls[h * 256 + (srow ^ ((h & 7) << 3))] = val;
      }
    }
  }
  __syncthreads();

  // ---- attention phase (flash, per-wave independent, 16-row q-tile) ----
  bf16x8 a_q[2];
#pragma unroll
  for (int ks = 0; ks < 2; ++ks) {
    const int srow = wbase + l15;
    a_q[ks] = *reinterpret_cast<const bf16x8*>(
        Qls + srow * 64 + ((ks * 32 + lg * 8) ^ ((srow & 7) << 3)));
  }

  f32x4 o[4];
  float mrun[4], lrun[4];
#pragma unroll
  for (int r = 0; r < 4; ++r) {
    mrun[r] = -3.0e38f;
    lrun[r] = 0.f;
#pragma unroll
    for (int hi = 0; hi < 4; ++hi) o[hi][r] = 0.f;
  }

  unsigned short* Pw = Pls + w * 640;  // per-wave [16][40]
  const int njmax = qt >> 1;

  for (int j = 0; j <= njmax; ++j) {
    f32x4 s_acc[2];
#pragma unroll
    for (int si = 0; si < 2; ++si)
#pragma unroll
      for (int r = 0; r < 4; ++r) s_acc[si][r] = 0.f;

#pragma unroll
    for (int ks = 0; ks < 2; ++ks) {
      bf16x8 bk[2];
#pragma unroll
      for (int si = 0; si < 2; ++si) {
        const int srow = j * 32 + si * 16 + l15;
        const int kel = ks * 32 + lg * 8;
        bk[si] = *reinterpret_cast<const bf16x8*>(
            Kls + srow * 64 + (kel ^ ((srow & 7) << 3)));
      }
#pragma unroll
      for (int si = 0; si < 2; ++si)
        s_acc[si] = __builtin_amdgcn_mfma_f32_16x16x32_bf16(
            a_q[ks], bk[si], s_acc[si], 0, 0, 0);
    }

    const bool dlast = (j == njmax);
#pragma unroll
    for (int r = 0; r < 4; ++r) {
      const int mloc = lg * 4 + r;
      float v0 = s_acc[0][r] * 0.125f;
      float v1 = s_acc[1][r] * 0.125f;
      if (dlast) {
        if ((qt & 1) == 0) {
          if (l15 > mloc) v0 = -3.0e38f;
          v1 = -3.0e38f;  // whole upper half-block is future
        } else {
          if (l15 > mloc) v1 = -3.0e38f;
        }
      }
      float pm = fmaxf(v0, v1);
      pm = fmaxf(pm, __shfl_xor(pm, 1, 16));
      pm = fmaxf(pm, __shfl_xor(pm, 2, 16));
      pm = fmaxf(pm, __shfl_xor(pm, 4, 16));
      pm = fmaxf(pm, __shfl_xor(pm, 8, 16));
      const float mnew = fmaxf(mrun[r], pm);
      const float alpha = __expf(mrun[r] - mnew);
      mrun[r] = mnew;
      const float p0 = __expf(v0 - mnew);
      const float p1 = __expf(v1 - mnew);
      float ps = p0 + p1;
      ps += __shfl_xor(ps, 1, 16);
      ps += __shfl_xor(ps, 2, 16);
      ps += __shfl_xor(ps, 4, 16);
      ps += __shfl_xor(ps, 8, 16);
      lrun[r] = lrun[r] * alpha + ps;
#pragma unroll
      for (int hi = 0; hi < 4; ++hi) o[hi][r] *= alpha;
      Pw[mloc * 40 + l15] = f2bf(p0);
      Pw[mloc * 40 + 16 + l15] = f2bf(p1);
    }

    const bf16x8 pa =
        *reinterpret_cast<const bf16x8*>(Pw + l15 * 40 + lg * 8);
#pragma unroll
    for (int hi = 0; hi < 4; ++hi) {
      const int h = hi * 16 + l15;
      const int sel = j * 32 + lg * 8;
      const bf16x8 bv = *reinterpret_cast<const bf16x8*>(
          Vtls + h * 256 + (sel ^ ((h & 7) << 3)));
      o[hi] = __builtin_amdgcn_mfma_f32_16x16x32_bf16(pa, bv, o[hi], 0, 0, 0);
    }
  }

  // ---- out store ----
  float* og = out + ((size_t)b * NT + wbase) * NH;
#pragma unroll
  for (int r = 0; r < 4; ++r) {
    const float inv = 1.f / lrun[r];
    const int m = lg * 4 + r;
#pragma unroll
    for (int hi = 0; hi < 4; ++hi)
      og[m * 64 + hi * 16 + l15] = o[hi][r] * inv;
  }
}

// ---------------------------------------------------------------------------
extern "C" void kernel_launch(void* const* d_in, const int* in_sizes, int n_in,
                              void* d_out, int out_size, void* d_ws,
                              size_t ws_size, hipStream_t stream) {
  const float* x  = (const float*)d_in[0];
  const float* Wq = (const float*)d_in[1];
  const float* Wk = (const float*)d_in[2];
  const float* Wv = (const float*)d_in[3];
  unsigned short* Wt2 = (unsigned short*)d_ws;  // 147 KB, fragment-major
  float* out = (float*)d_out;

  w_prep_kernel<<<dim3((WT_ELEMS + 255) / 256), dim3(256), 0, stream>>>(
      Wq, Wk, Wv, Wt2);
  fused_qkv_attn_kernel<<<dim3(NB), dim3(1024), 0, stream>>>(x, Wt2, out);
}